// Round 1
// baseline (827.773 us; speedup 1.0000x reference)
//
#include <hip/hip_runtime.h>

#define DIM 128

// One 64-lane wave per edge: gather x[src] (512B coalesced), atomicAdd into agg[dst].
__global__ void scatter_kernel(const float* __restrict__ x,
                               const int* __restrict__ ei,
                               float* __restrict__ agg,
                               float* __restrict__ deg,
                               int E) {
    int gid = blockIdx.x * blockDim.x + threadIdx.x;
    int e = gid >> 6;
    int lane = gid & 63;
    if (e >= E) return;
    int src = ei[e];
    int dst = ei[E + e];
    const float2 v = reinterpret_cast<const float2*>(x + (size_t)src * DIM)[lane];
    float* ag = agg + (size_t)dst * DIM + lane * 2;
    atomicAdd(ag, v.x);
    atomicAdd(ag + 1, v.y);
    if (lane == 0) atomicAdd(deg + dst, 1.0f);
}

#define ROWS_PER_BLOCK 16

// out[r] = x[r] @ Ws^T + b_s + (agg[r]/max(deg,1)) @ Wn^T + b_n, in place (agg == out).
// 256 threads: j = t&127 owns output column j for 8 rows (rblk = t>>7 picks row half).
// x/mean rows staged in LDS, read as same-address broadcasts (free). Weights streamed
// float4 from global (L1/L2-hot, 128KB total working set).
__global__ void finalize_kernel(const float* __restrict__ x,
                                const float* __restrict__ agg,
                                const float* __restrict__ deg,
                                const float* __restrict__ w_self,
                                const float* __restrict__ b_self,
                                const float* __restrict__ w_neigh,
                                const float* __restrict__ b_neigh,
                                float* __restrict__ out,
                                int n) {
    __shared__ float xs[ROWS_PER_BLOCK][DIM];
    __shared__ float ms[ROWS_PER_BLOCK][DIM];
    int base = blockIdx.x * ROWS_PER_BLOCK;
    int t = threadIdx.x;

    // Stage 16 rows of x and mean=agg/deg into LDS (coalesced float4).
    for (int fi = t; fi < ROWS_PER_BLOCK * DIM / 4; fi += blockDim.x) {
        int row = fi >> 5;   // 32 float4 per row
        int c4 = fi & 31;
        int grow = base + row;
        if (grow < n) {
            float4 xv = reinterpret_cast<const float4*>(x + (size_t)grow * DIM)[c4];
            float4 av = reinterpret_cast<const float4*>(agg + (size_t)grow * DIM)[c4];
            float d = deg[grow];
            d = d > 1.0f ? d : 1.0f;
            float inv = 1.0f / d;
            reinterpret_cast<float4*>(xs[row])[c4] = xv;
            float4 mv = make_float4(av.x * inv, av.y * inv, av.z * inv, av.w * inv);
            reinterpret_cast<float4*>(ms[row])[c4] = mv;
        }
    }
    __syncthreads();

    int j = t & 127;
    int rblk = t >> 7;  // 0..1
    float acc[8];
    float bias = b_self[j] + b_neigh[j];
#pragma unroll
    for (int i = 0; i < 8; ++i) acc[i] = bias;

    const float4* wsr = reinterpret_cast<const float4*>(w_self + (size_t)j * DIM);
    const float4* wnr = reinterpret_cast<const float4*>(w_neigh + (size_t)j * DIM);

    for (int kk = 0; kk < DIM / 4; ++kk) {
        float4 ws4 = wsr[kk];
        float4 wn4 = wnr[kk];
#pragma unroll
        for (int i = 0; i < 8; ++i) {
            int rl = rblk * 8 + i;
            float4 xv = reinterpret_cast<const float4*>(xs[rl])[kk];
            float4 mv = reinterpret_cast<const float4*>(ms[rl])[kk];
            acc[i] += ws4.x * xv.x + ws4.y * xv.y + ws4.z * xv.z + ws4.w * xv.w
                    + wn4.x * mv.x + wn4.y * mv.y + wn4.z * mv.z + wn4.w * mv.w;
        }
    }

#pragma unroll
    for (int i = 0; i < 8; ++i) {
        int grow = base + rblk * 8 + i;
        if (grow < n) out[(size_t)grow * DIM + j] = acc[i];
    }
}

extern "C" void kernel_launch(void* const* d_in, const int* in_sizes, int n_in,
                              void* d_out, int out_size, void* d_ws, size_t ws_size,
                              hipStream_t stream) {
    const float* x       = (const float*)d_in[0];
    const int*   ei      = (const int*)d_in[1];
    const float* w_self  = (const float*)d_in[2];
    const float* b_self  = (const float*)d_in[3];
    const float* w_neigh = (const float*)d_in[4];
    const float* b_neigh = (const float*)d_in[5];
    float* out = (float*)d_out;
    float* deg = (float*)d_ws;

    int n = in_sizes[0] / DIM;
    int E = in_sizes[1] / 2;

    // agg accumulates directly into d_out; zero it + deg each call (harness poisons).
    hipMemsetAsync(out, 0, (size_t)n * DIM * sizeof(float), stream);
    hipMemsetAsync(deg, 0, (size_t)n * sizeof(float), stream);

    // One wave per edge -> E/4 blocks of 256 threads.
    int sblocks = (E + 3) / 4;
    scatter_kernel<<<sblocks, 256, 0, stream>>>(x, ei, out, deg, E);

    int fblocks = (n + ROWS_PER_BLOCK - 1) / ROWS_PER_BLOCK;
    finalize_kernel<<<fblocks, 256, 0, stream>>>(x, out, deg, w_self, b_self,
                                                 w_neigh, b_neigh, out, n);
}

// Round 2
// 386.824 us; speedup vs baseline: 2.1399x; 2.1399x over previous
//
#include <hip/hip_runtime.h>

#define DIM 128
#define NT 256

// Pass A: in-degree histogram (int atomics, 800k ops — cheap vs 102M fp32).
__global__ void hist_kernel(const int* __restrict__ ei, int* __restrict__ cnt, int E) {
    for (int e = blockIdx.x * blockDim.x + threadIdx.x; e < E; e += gridDim.x * blockDim.x)
        atomicAdd(&cnt[ei[E + e]], 1);
}

// Pass B: single-block exclusive scan of cnt -> offs, and seed cursor = offs.
__global__ void scan_kernel(const int* __restrict__ cnt, int* __restrict__ offs,
                            int* __restrict__ cursor, int n, int E) {
    __shared__ int part[NT];
    int t = threadIdx.x;
    int chunk = (n + NT - 1) / NT;
    int lo = t * chunk, hi = min(n, lo + chunk);
    int s = 0;
    for (int i = lo; i < hi; ++i) s += cnt[i];
    part[t] = s;
    __syncthreads();
    for (int d = 1; d < NT; d <<= 1) {
        int v = (t >= d) ? part[t - d] : 0;
        __syncthreads();
        part[t] += v;
        __syncthreads();
    }
    int run = (t == 0) ? 0 : part[t - 1];
    for (int i = lo; i < hi; ++i) {
        offs[i] = run;
        cursor[i] = run;
        run += cnt[i];
    }
    if (t == 0) offs[n] = E;
}

// Pass C: bucket-fill edge sources by dst.
__global__ void fill_kernel(const int* __restrict__ ei, int* __restrict__ cursor,
                            int* __restrict__ csr, int E) {
    for (int e = blockIdx.x * blockDim.x + threadIdx.x; e < E; e += gridDim.x * blockDim.x) {
        int dst = ei[E + e];
        int pos = atomicAdd(&cursor[dst], 1);
        csr[pos] = ei[e];
    }
}

// Pass D: pull-aggregate. One 64-lane wave per dst node; lane holds float2 (2 cols).
// Gathers x[src] rows (L2/L3-resident), writes the MEAN row to out — no fp32 atomics.
__global__ void aggregate_kernel(const float* __restrict__ x, const int* __restrict__ offs,
                                 const int* __restrict__ csr, float* __restrict__ out, int n) {
    int wave = threadIdx.x >> 6;
    int lane = threadIdx.x & 63;
    int node = blockIdx.x * (blockDim.x >> 6) + wave;
    if (node >= n) return;
    int start = offs[node], end = offs[node + 1];
    float2 acc = make_float2(0.f, 0.f);
    int e = start;
    for (; e + 1 < end; e += 2) {  // 2 gathers in flight
        int s0 = csr[e], s1 = csr[e + 1];
        float2 v0 = reinterpret_cast<const float2*>(x + (size_t)s0 * DIM)[lane];
        float2 v1 = reinterpret_cast<const float2*>(x + (size_t)s1 * DIM)[lane];
        acc.x += v0.x + v1.x;
        acc.y += v0.y + v1.y;
    }
    if (e < end) {
        int s0 = csr[e];
        float2 v0 = reinterpret_cast<const float2*>(x + (size_t)s0 * DIM)[lane];
        acc.x += v0.x;
        acc.y += v0.y;
    }
    float d = (float)(end - start);
    float inv = d > 0.f ? 1.0f / d : 0.f;
    reinterpret_cast<float2*>(out + (size_t)node * DIM)[lane] =
        make_float2(acc.x * inv, acc.y * inv);
}

#define ROWS_PER_BLOCK 16

// out[r] = x[r] @ Ws^T + b_s + mean[r] @ Wn^T + b_n, in place (mean == out).
// Each block reads only its own 16 rows before overwriting them — in-place safe.
__global__ void finalize_kernel(const float* __restrict__ x,
                                const float* __restrict__ mean,
                                const float* __restrict__ w_self,
                                const float* __restrict__ b_self,
                                const float* __restrict__ w_neigh,
                                const float* __restrict__ b_neigh,
                                float* __restrict__ out,
                                int n) {
    __shared__ float xs[ROWS_PER_BLOCK][DIM];
    __shared__ float ms[ROWS_PER_BLOCK][DIM];
    int base = blockIdx.x * ROWS_PER_BLOCK;
    int t = threadIdx.x;

    for (int fi = t; fi < ROWS_PER_BLOCK * DIM / 4; fi += blockDim.x) {
        int row = fi >> 5;  // 32 float4 per row
        int c4 = fi & 31;
        int grow = base + row;
        if (grow < n) {
            float4 xv = reinterpret_cast<const float4*>(x + (size_t)grow * DIM)[c4];
            float4 mv = reinterpret_cast<const float4*>(mean + (size_t)grow * DIM)[c4];
            reinterpret_cast<float4*>(xs[row])[c4] = xv;
            reinterpret_cast<float4*>(ms[row])[c4] = mv;
        }
    }
    __syncthreads();

    int j = t & 127;
    int rblk = t >> 7;  // 0..1
    float acc[8];
    float bias = b_self[j] + b_neigh[j];
#pragma unroll
    for (int i = 0; i < 8; ++i) acc[i] = bias;

    const float4* wsr = reinterpret_cast<const float4*>(w_self + (size_t)j * DIM);
    const float4* wnr = reinterpret_cast<const float4*>(w_neigh + (size_t)j * DIM);

    for (int kk = 0; kk < DIM / 4; ++kk) {
        float4 ws4 = wsr[kk];
        float4 wn4 = wnr[kk];
#pragma unroll
        for (int i = 0; i < 8; ++i) {
            int rl = rblk * 8 + i;
            float4 xv = reinterpret_cast<const float4*>(xs[rl])[kk];
            float4 mv = reinterpret_cast<const float4*>(ms[rl])[kk];
            acc[i] += ws4.x * xv.x + ws4.y * xv.y + ws4.z * xv.z + ws4.w * xv.w
                    + wn4.x * mv.x + wn4.y * mv.y + wn4.z * mv.z + wn4.w * mv.w;
        }
    }

#pragma unroll
    for (int i = 0; i < 8; ++i) {
        int grow = base + rblk * 8 + i;
        if (grow < n) out[(size_t)grow * DIM + j] = acc[i];
    }
}

extern "C" void kernel_launch(void* const* d_in, const int* in_sizes, int n_in,
                              void* d_out, int out_size, void* d_ws, size_t ws_size,
                              hipStream_t stream) {
    const float* x       = (const float*)d_in[0];
    const int*   ei      = (const int*)d_in[1];
    const float* w_self  = (const float*)d_in[2];
    const float* b_self  = (const float*)d_in[3];
    const float* w_neigh = (const float*)d_in[4];
    const float* b_neigh = (const float*)d_in[5];
    float* out = (float*)d_out;

    int n = in_sizes[0] / DIM;
    int E = in_sizes[1] / 2;

    // Workspace layout (ints): cnt[n] | offs[n+1] | cursor[n] | csr[E]  (~3.8 MB)
    int* cnt    = (int*)d_ws;
    int* offs   = cnt + n;
    int* cursor = offs + n + 1;
    int* csr    = cursor + n;

    hipMemsetAsync(cnt, 0, (size_t)n * sizeof(int), stream);

    int eblocks = (E + NT - 1) / NT;
    hist_kernel<<<eblocks, NT, 0, stream>>>(ei, cnt, E);
    scan_kernel<<<1, NT, 0, stream>>>(cnt, offs, cursor, n, E);
    fill_kernel<<<eblocks, NT, 0, stream>>>(ei, cursor, csr, E);

    int ablocks = (n + 3) / 4;  // 4 waves/block, 1 node/wave
    aggregate_kernel<<<ablocks, NT, 0, stream>>>(x, offs, csr, out, n);

    int fblocks = (n + ROWS_PER_BLOCK - 1) / ROWS_PER_BLOCK;
    finalize_kernel<<<fblocks, NT, 0, stream>>>(x, out, w_self, b_self,
                                                w_neigh, b_neigh, out, n);
}

// Round 3
// 294.938 us; speedup vs baseline: 2.8066x; 1.3115x over previous
//
#include <hip/hip_runtime.h>

#define DIM 128
#define NT 256

typedef __attribute__((ext_vector_type(8))) short short8;
typedef __attribute__((ext_vector_type(4))) float f32x4;

static __device__ __forceinline__ unsigned short f32_to_bf16(float f) {
    union { float f; unsigned int u; } c; c.f = f;
    unsigned int u = c.u;
    u += 0x7FFFu + ((u >> 16) & 1u);   // RNE
    return (unsigned short)(u >> 16);
}

// Pass A: in-degree histogram.
__global__ void hist_kernel(const int* __restrict__ ei, int* __restrict__ cnt, int E) {
    for (int e = blockIdx.x * blockDim.x + threadIdx.x; e < E; e += gridDim.x * blockDim.x)
        atomicAdd(&cnt[ei[E + e]], 1);
}

// Pass B: single-block exclusive scan (1024 threads).
#define NSCAN 1024
__global__ void scan_kernel(const int* __restrict__ cnt, int* __restrict__ offs,
                            int* __restrict__ cursor, int n, int E) {
    __shared__ int part[NSCAN];
    int t = threadIdx.x;
    int chunk = (n + NSCAN - 1) / NSCAN;
    int lo = t * chunk, hi = min(n, lo + chunk);
    int s = 0;
    for (int i = lo; i < hi; ++i) s += cnt[i];
    part[t] = s;
    __syncthreads();
    for (int d = 1; d < NSCAN; d <<= 1) {
        int v = (t >= d) ? part[t - d] : 0;
        __syncthreads();
        part[t] += v;
        __syncthreads();
    }
    int run = (t == 0) ? 0 : part[t - 1];
    for (int i = lo; i < hi; ++i) {
        offs[i] = run;
        cursor[i] = run;
        run += cnt[i];
    }
    if (t == 0) offs[n] = E;
}

// Pass C: bucket-fill edge sources by dst.
__global__ void fill_kernel(const int* __restrict__ ei, int* __restrict__ cursor,
                            int* __restrict__ csr, int E) {
    for (int e = blockIdx.x * blockDim.x + threadIdx.x; e < E; e += gridDim.x * blockDim.x) {
        int dst = ei[E + e];
        int pos = atomicAdd(&cursor[dst], 1);
        csr[pos] = ei[e];
    }
}

// Pass D: pull-aggregate, one wave per dst node, mean written to out (fp32).
__global__ void aggregate_kernel(const float* __restrict__ x, const int* __restrict__ offs,
                                 const int* __restrict__ csr, float* __restrict__ out, int n) {
    int wave = threadIdx.x >> 6;
    int lane = threadIdx.x & 63;
    int node = blockIdx.x * (blockDim.x >> 6) + wave;
    if (node >= n) return;
    int start = offs[node], end = offs[node + 1];
    float2 acc = make_float2(0.f, 0.f);
    int e = start;
    for (; e + 1 < end; e += 2) {
        int s0 = csr[e], s1 = csr[e + 1];
        float2 v0 = reinterpret_cast<const float2*>(x + (size_t)s0 * DIM)[lane];
        float2 v1 = reinterpret_cast<const float2*>(x + (size_t)s1 * DIM)[lane];
        acc.x += v0.x + v1.x;
        acc.y += v0.y + v1.y;
    }
    if (e < end) {
        int s0 = csr[e];
        float2 v0 = reinterpret_cast<const float2*>(x + (size_t)s0 * DIM)[lane];
        acc.x += v0.x;
        acc.y += v0.y;
    }
    float d = (float)(end - start);
    float inv = d > 0.f ? 1.0f / d : 0.f;
    reinterpret_cast<float2*>(out + (size_t)node * DIM)[lane] =
        make_float2(acc.x * inv, acc.y * inv);
}

// Prep: pack W_B[k][j] (k<128: w_self[j][k]; else w_neigh[j][k-128]) into bf16
// fragment order for mfma_16x16x32 B-operand: frag f=(ks*8+nf), lane l, elem e:
// k = ks*32 + (l>>4)*8 + e, j = nf*16 + (l&15). Per-lane 8 bf16 = 16B contiguous.
// Also combined bias.
__global__ void prep_kernel(const float* __restrict__ w_self, const float* __restrict__ b_self,
                            const float* __restrict__ w_neigh, const float* __restrict__ b_neigh,
                            unsigned short* __restrict__ w_swz, float* __restrict__ bias) {
    int g = blockIdx.x * blockDim.x + threadIdx.x;   // 4096 slots
    if (g < 128) bias[g] = b_self[g] + b_neigh[g];
    if (g >= 64 * 64) return;
    int f = g >> 6, l = g & 63;
    int ks = f >> 3, nf = f & 7;
    int j = nf * 16 + (l & 15);
    int kbase = ks * 32 + ((l >> 4) << 3);
#pragma unroll
    for (int e = 0; e < 8; ++e) {
        int k = kbase + e;
        float v = (k < 128) ? w_self[(size_t)j * 128 + k] : w_neigh[(size_t)j * 128 + (k - 128)];
        w_swz[((size_t)g << 3) + e] = f32_to_bf16(v);
    }
}

// MFMA finalize: out[64-row tile] = [x|mean]_bf16 @ W_B + bias. In place (mean == out):
// tile staged to LDS before any store. 4 waves, each owns 16 rows x 128 cols.
#define FROWS 64
__global__ void finalize_kernel(const float* __restrict__ x,
                                const float* __restrict__ mean,
                                const unsigned short* __restrict__ w_swz,
                                const float* __restrict__ bias,
                                float* __restrict__ out, int n) {
    __shared__ unsigned short xm[FROWS][264];   // 256 bf16 K + 8 pad (stride 132 dw -> 2-way max)
    int t = threadIdx.x;
    int base = blockIdx.x * FROWS;

    // Stage: 64 rows x 128 f32 from each of x and mean -> bf16 LDS, K-concat.
    for (int fi = t; fi < FROWS * 32; fi += NT) {
        int row = fi >> 5, c4 = fi & 31;
        int grow = base + row;
        ushort4 sx = {0, 0, 0, 0}, sm = {0, 0, 0, 0};
        if (grow < n) {
            float4 xv = reinterpret_cast<const float4*>(x + (size_t)grow * DIM)[c4];
            float4 mv = reinterpret_cast<const float4*>(mean + (size_t)grow * DIM)[c4];
            sx = make_ushort4(f32_to_bf16(xv.x), f32_to_bf16(xv.y), f32_to_bf16(xv.z), f32_to_bf16(xv.w));
            sm = make_ushort4(f32_to_bf16(mv.x), f32_to_bf16(mv.y), f32_to_bf16(mv.z), f32_to_bf16(mv.w));
        }
        *reinterpret_cast<ushort4*>(&xm[row][c4 * 4]) = sx;
        *reinterpret_cast<ushort4*>(&xm[row][128 + c4 * 4]) = sm;
    }
    __syncthreads();

    int wave = t >> 6, lane = t & 63;
    int wrow = wave * 16;                       // wave's 16 rows
    int arow = wrow + (lane & 15);
    int koff = (lane >> 4) << 3;                // lane-group k offset within 32

    f32x4 acc[8];
#pragma unroll
    for (int nf = 0; nf < 8; ++nf) acc[nf] = (f32x4){0.f, 0.f, 0.f, 0.f};

#pragma unroll
    for (int ks = 0; ks < 8; ++ks) {
        short8 a = *reinterpret_cast<const short8*>(&xm[arow][ks * 32 + koff]);
#pragma unroll
        for (int nf = 0; nf < 8; ++nf) {
            short8 b = *reinterpret_cast<const short8*>(
                w_swz + ((((size_t)ks * 8 + nf) * 64 + lane) << 3));
            acc[nf] = __builtin_amdgcn_mfma_f32_16x16x32_bf16(a, b, acc[nf], 0, 0, 0);
        }
    }

    // Epilogue: C/D layout col=lane&15, row=(lane>>4)*4+r (m89-verified).
    int crow0 = wrow + ((lane >> 4) << 2);
#pragma unroll
    for (int nf = 0; nf < 8; ++nf) {
        int col = nf * 16 + (lane & 15);
        float bs = bias[col];
#pragma unroll
        for (int r = 0; r < 4; ++r) {
            int grow = base + crow0 + r;
            if (grow < n) out[(size_t)grow * DIM + col] = acc[nf][r] + bs;
        }
    }
}

extern "C" void kernel_launch(void* const* d_in, const int* in_sizes, int n_in,
                              void* d_out, int out_size, void* d_ws, size_t ws_size,
                              hipStream_t stream) {
    const float* x       = (const float*)d_in[0];
    const int*   ei      = (const int*)d_in[1];
    const float* w_self  = (const float*)d_in[2];
    const float* b_self  = (const float*)d_in[3];
    const float* w_neigh = (const float*)d_in[4];
    const float* b_neigh = (const float*)d_in[5];
    float* out = (float*)d_out;

    int n = in_sizes[0] / DIM;
    int E = in_sizes[1] / 2;

    // ws: cnt[n] | offs[n+1] | cursor[n] | csr[E] | (16B align) w_swz bf16[32768] | bias f32[128]
    int* cnt    = (int*)d_ws;
    int* offs   = cnt + n;
    int* cursor = offs + n + 1;
    int* csr    = cursor + n;
    unsigned short* w_swz = (unsigned short*)(((uintptr_t)(csr + E) + 15) & ~(uintptr_t)15);
    float* bias = (float*)(w_swz + 64 * 64 * 8);

    hipMemsetAsync(cnt, 0, (size_t)n * sizeof(int), stream);

    prep_kernel<<<16, 256, 0, stream>>>(w_self, b_self, w_neigh, b_neigh, w_swz, bias);

    int eblocks = (E + NT - 1) / NT;
    hist_kernel<<<eblocks, NT, 0, stream>>>(ei, cnt, E);
    scan_kernel<<<1, NSCAN, 0, stream>>>(cnt, offs, cursor, n, E);
    fill_kernel<<<eblocks, NT, 0, stream>>>(ei, cursor, csr, E);

    int ablocks = (n + 3) / 4;  // 1 node/wave, 4 waves/block
    aggregate_kernel<<<ablocks, NT, 0, stream>>>(x, offs, csr, out, n);

    int fblocks = (n + FROWS - 1) / FROWS;
    finalize_kernel<<<fblocks, NT, 0, stream>>>(x, out, w_swz, bias, out, n);
}

// Round 4
// 192.435 us; speedup vs baseline: 4.3016x; 1.5327x over previous
//
#include <hip/hip_runtime.h>

#define DIM 128
#define NT 256

typedef __attribute__((ext_vector_type(8))) short short8;
typedef __attribute__((ext_vector_type(4))) float f32x4;

static __device__ __forceinline__ unsigned short f32_to_bf16(float f) {
    union { float f; unsigned int u; } c; c.f = f;
    unsigned int u = c.u;
    u += 0x7FFFu + ((u >> 16) & 1u);   // RNE
    return (unsigned short)(u >> 16);
}

// Pass A: in-degree histogram.
__global__ void hist_kernel(const int* __restrict__ ei, int* __restrict__ cnt, int E) {
    for (int e = blockIdx.x * blockDim.x + threadIdx.x; e < E; e += gridDim.x * blockDim.x)
        atomicAdd(&cnt[ei[E + e]], 1);
}

// Pass B: hierarchical exclusive scan (3 small parallel kernels).
__global__ void scan1_kernel(const int* __restrict__ cnt, int* __restrict__ offs,
                             int* __restrict__ bsum, int n) {
    __shared__ int sh[NT];
    int i = blockIdx.x * NT + threadIdx.x;
    int v = (i < n) ? cnt[i] : 0;
    sh[threadIdx.x] = v;
    __syncthreads();
    for (int d = 1; d < NT; d <<= 1) {
        int t = (threadIdx.x >= d) ? sh[threadIdx.x - d] : 0;
        __syncthreads();
        sh[threadIdx.x] += t;
        __syncthreads();
    }
    if (i < n) offs[i] = sh[threadIdx.x] - v;      // block-local exclusive
    if (threadIdx.x == NT - 1) bsum[blockIdx.x] = sh[NT - 1];
}

__global__ void scan2_kernel(int* __restrict__ bsum, int nb) {
    __shared__ int sh[NT];
    int v = (threadIdx.x < nb) ? bsum[threadIdx.x] : 0;
    sh[threadIdx.x] = v;
    __syncthreads();
    for (int d = 1; d < NT; d <<= 1) {
        int t = (threadIdx.x >= d) ? sh[threadIdx.x - d] : 0;
        __syncthreads();
        sh[threadIdx.x] += t;
        __syncthreads();
    }
    if (threadIdx.x < nb) bsum[threadIdx.x] = sh[threadIdx.x] - v;  // exclusive
}

__global__ void scan3_kernel(int* __restrict__ offs, const int* __restrict__ bsum,
                             int* __restrict__ cursor, int n, int E) {
    int i = blockIdx.x * NT + threadIdx.x;
    if (i < n) {
        int o = offs[i] + bsum[blockIdx.x];
        offs[i] = o;
        cursor[i] = o;
    }
    if (i == 0) offs[n] = E;
}

// Pass C: bucket-fill edge sources by dst.
__global__ void fill_kernel(const int* __restrict__ ei, int* __restrict__ cursor,
                            int* __restrict__ csr, int E) {
    for (int e = blockIdx.x * blockDim.x + threadIdx.x; e < E; e += gridDim.x * blockDim.x) {
        int dst = ei[E + e];
        int pos = atomicAdd(&cursor[dst], 1);
        csr[pos] = ei[e];
    }
}

// Pass D: pull-aggregate, one wave per dst node, mean written to out (fp32).
__global__ void aggregate_kernel(const float* __restrict__ x, const int* __restrict__ offs,
                                 const int* __restrict__ csr, float* __restrict__ out, int n) {
    int wave = threadIdx.x >> 6;
    int lane = threadIdx.x & 63;
    int node = blockIdx.x * (blockDim.x >> 6) + wave;
    if (node >= n) return;
    int start = offs[node], end = offs[node + 1];
    float2 acc = make_float2(0.f, 0.f);
    int e = start;
    for (; e + 3 < end; e += 4) {   // 4 gathers in flight
        int s0 = csr[e], s1 = csr[e + 1], s2 = csr[e + 2], s3 = csr[e + 3];
        float2 v0 = reinterpret_cast<const float2*>(x + (size_t)s0 * DIM)[lane];
        float2 v1 = reinterpret_cast<const float2*>(x + (size_t)s1 * DIM)[lane];
        float2 v2 = reinterpret_cast<const float2*>(x + (size_t)s2 * DIM)[lane];
        float2 v3 = reinterpret_cast<const float2*>(x + (size_t)s3 * DIM)[lane];
        acc.x += (v0.x + v1.x) + (v2.x + v3.x);
        acc.y += (v0.y + v1.y) + (v2.y + v3.y);
    }
    for (; e < end; ++e) {
        int s0 = csr[e];
        float2 v0 = reinterpret_cast<const float2*>(x + (size_t)s0 * DIM)[lane];
        acc.x += v0.x;
        acc.y += v0.y;
    }
    float d = (float)(end - start);
    float inv = d > 0.f ? 1.0f / d : 0.f;
    reinterpret_cast<float2*>(out + (size_t)node * DIM)[lane] =
        make_float2(acc.x * inv, acc.y * inv);
}

// Prep: pack W_B into bf16 MFMA B-fragment order + combined bias.
__global__ void prep_kernel(const float* __restrict__ w_self, const float* __restrict__ b_self,
                            const float* __restrict__ w_neigh, const float* __restrict__ b_neigh,
                            unsigned short* __restrict__ w_swz, float* __restrict__ bias) {
    int g = blockIdx.x * blockDim.x + threadIdx.x;   // 4096 slots
    if (g < 128) bias[g] = b_self[g] + b_neigh[g];
    if (g >= 64 * 64) return;
    int f = g >> 6, l = g & 63;
    int ks = f >> 3, nf = f & 7;
    int j = nf * 16 + (l & 15);
    int kbase = ks * 32 + ((l >> 4) << 3);
#pragma unroll
    for (int e = 0; e < 8; ++e) {
        int k = kbase + e;
        float v = (k < 128) ? w_self[(size_t)j * 128 + k] : w_neigh[(size_t)j * 128 + (k - 128)];
        w_swz[((size_t)g << 3) + e] = f32_to_bf16(v);
    }
}

// MFMA finalize: out[64-row tile] = [x|mean]_bf16 @ W_B + bias, in place (mean == out).
#define FROWS 64
__global__ void finalize_kernel(const float* __restrict__ x,
                                const float* __restrict__ mean,
                                const unsigned short* __restrict__ w_swz,
                                const float* __restrict__ bias,
                                float* __restrict__ out, int n) {
    __shared__ unsigned short xm[FROWS][264];   // stride 132 dw -> 2-way max (free)
    int t = threadIdx.x;
    int base = blockIdx.x * FROWS;

    for (int fi = t; fi < FROWS * 32; fi += NT) {
        int row = fi >> 5, c4 = fi & 31;
        int grow = base + row;
        ushort4 sx = {0, 0, 0, 0}, sm = {0, 0, 0, 0};
        if (grow < n) {
            float4 xv = reinterpret_cast<const float4*>(x + (size_t)grow * DIM)[c4];
            float4 mv = reinterpret_cast<const float4*>(mean + (size_t)grow * DIM)[c4];
            sx = make_ushort4(f32_to_bf16(xv.x), f32_to_bf16(xv.y), f32_to_bf16(xv.z), f32_to_bf16(xv.w));
            sm = make_ushort4(f32_to_bf16(mv.x), f32_to_bf16(mv.y), f32_to_bf16(mv.z), f32_to_bf16(mv.w));
        }
        *reinterpret_cast<ushort4*>(&xm[row][c4 * 4]) = sx;
        *reinterpret_cast<ushort4*>(&xm[row][128 + c4 * 4]) = sm;
    }
    __syncthreads();

    int wave = t >> 6, lane = t & 63;
    int wrow = wave * 16;
    int arow = wrow + (lane & 15);
    int koff = (lane >> 4) << 3;

    f32x4 acc[8];
#pragma unroll
    for (int nf = 0; nf < 8; ++nf) acc[nf] = (f32x4){0.f, 0.f, 0.f, 0.f};

#pragma unroll
    for (int ks = 0; ks < 8; ++ks) {
        short8 a = *reinterpret_cast<const short8*>(&xm[arow][ks * 32 + koff]);
#pragma unroll
        for (int nf = 0; nf < 8; ++nf) {
            short8 b = *reinterpret_cast<const short8*>(
                w_swz + ((((size_t)ks * 8 + nf) * 64 + lane) << 3));
            acc[nf] = __builtin_amdgcn_mfma_f32_16x16x32_bf16(a, b, acc[nf], 0, 0, 0);
        }
    }

    int crow0 = wrow + ((lane >> 4) << 2);
#pragma unroll
    for (int nf = 0; nf < 8; ++nf) {
        int col = nf * 16 + (lane & 15);
        float bs = bias[col];
#pragma unroll
        for (int r = 0; r < 4; ++r) {
            int grow = base + crow0 + r;
            if (grow < n) out[(size_t)grow * DIM + col] = acc[nf][r] + bs;
        }
    }
}

extern "C" void kernel_launch(void* const* d_in, const int* in_sizes, int n_in,
                              void* d_out, int out_size, void* d_ws, size_t ws_size,
                              hipStream_t stream) {
    const float* x       = (const float*)d_in[0];
    const int*   ei      = (const int*)d_in[1];
    const float* w_self  = (const float*)d_in[2];
    const float* b_self  = (const float*)d_in[3];
    const float* w_neigh = (const float*)d_in[4];
    const float* b_neigh = (const float*)d_in[5];
    float* out = (float*)d_out;

    int n = in_sizes[0] / DIM;
    int E = in_sizes[1] / 2;
    int nb = (n + NT - 1) / NT;   // 196 scan blocks (<= 256)

    // ws: cnt[n] | offs[n+1] | cursor[n] | bsum[256] | csr[E] | (align) w_swz bf16[32768] | bias f32[128]
    int* cnt    = (int*)d_ws;
    int* offs   = cnt + n;
    int* cursor = offs + n + 1;
    int* bsum   = cursor + n;
    int* csr    = bsum + 256;
    unsigned short* w_swz = (unsigned short*)(((uintptr_t)(csr + E) + 15) & ~(uintptr_t)15);
    float* bias = (float*)(w_swz + 64 * 64 * 8);

    hipMemsetAsync(cnt, 0, (size_t)n * sizeof(int), stream);

    prep_kernel<<<16, 256, 0, stream>>>(w_self, b_self, w_neigh, b_neigh, w_swz, bias);

    int eblocks = (E + NT - 1) / NT;
    hist_kernel<<<eblocks, NT, 0, stream>>>(ei, cnt, E);
    scan1_kernel<<<nb, NT, 0, stream>>>(cnt, offs, bsum, n);
    scan2_kernel<<<1, NT, 0, stream>>>(bsum, nb);
    scan3_kernel<<<nb, NT, 0, stream>>>(offs, bsum, cursor, n, E);
    fill_kernel<<<eblocks, NT, 0, stream>>>(ei, cursor, csr, E);

    int ablocks = (n + 3) / 4;  // 1 node/wave, 4 waves/block
    aggregate_kernel<<<ablocks, NT, 0, stream>>>(x, offs, csr, out, n);

    int fblocks = (n + FROWS - 1) / FROWS;
    finalize_kernel<<<fblocks, NT, 0, stream>>>(x, out, w_swz, bias, out, n);
}

// Round 5
// 182.998 us; speedup vs baseline: 4.5234x; 1.0516x over previous
//
#include <hip/hip_runtime.h>

#define DIM 128
#define NT 256

typedef __attribute__((ext_vector_type(8))) short short8;
typedef __attribute__((ext_vector_type(8))) unsigned short ushort8;
typedef __attribute__((ext_vector_type(4))) float f32x4;

static __device__ __forceinline__ unsigned short f32_to_bf16(float f) {
    union { float f; unsigned int u; } c; c.f = f;
    unsigned int u = c.u;
    u += 0x7FFFu + ((u >> 16) & 1u);   // RNE
    return (unsigned short)(u >> 16);
}
static __device__ __forceinline__ float bf16lo_to_f32(unsigned int v) {
    union { unsigned int u; float f; } c; c.u = v << 16; return c.f;
}
static __device__ __forceinline__ float bf16hi_to_f32(unsigned int v) {
    union { unsigned int u; float f; } c; c.u = v & 0xFFFF0000u; return c.f;
}

// x (f32) -> x_bf (bf16), float4 per thread.
__global__ void prepx_kernel(const float* __restrict__ x, unsigned short* __restrict__ xb, int n4) {
    int g = blockIdx.x * blockDim.x + threadIdx.x;
    if (g >= n4) return;
    float4 v = reinterpret_cast<const float4*>(x)[g];
    ushort4 s = make_ushort4(f32_to_bf16(v.x), f32_to_bf16(v.y), f32_to_bf16(v.z), f32_to_bf16(v.w));
    reinterpret_cast<ushort4*>(xb)[g] = s;
}

// Pass A: in-degree histogram.
__global__ void hist_kernel(const int* __restrict__ ei, int* __restrict__ cnt, int E) {
    for (int e = blockIdx.x * blockDim.x + threadIdx.x; e < E; e += gridDim.x * blockDim.x)
        atomicAdd(&cnt[ei[E + e]], 1);
}

// Pass B: hierarchical exclusive scan.
__global__ void scan1_kernel(const int* __restrict__ cnt, int* __restrict__ offs,
                             int* __restrict__ bsum, int n) {
    __shared__ int sh[NT];
    int i = blockIdx.x * NT + threadIdx.x;
    int v = (i < n) ? cnt[i] : 0;
    sh[threadIdx.x] = v;
    __syncthreads();
    for (int d = 1; d < NT; d <<= 1) {
        int t = (threadIdx.x >= d) ? sh[threadIdx.x - d] : 0;
        __syncthreads();
        sh[threadIdx.x] += t;
        __syncthreads();
    }
    if (i < n) offs[i] = sh[threadIdx.x] - v;
    if (threadIdx.x == NT - 1) bsum[blockIdx.x] = sh[NT - 1];
}

__global__ void scan2_kernel(int* __restrict__ bsum, int nb) {
    __shared__ int sh[NT];
    int v = (threadIdx.x < nb) ? bsum[threadIdx.x] : 0;
    sh[threadIdx.x] = v;
    __syncthreads();
    for (int d = 1; d < NT; d <<= 1) {
        int t = (threadIdx.x >= d) ? sh[threadIdx.x - d] : 0;
        __syncthreads();
        sh[threadIdx.x] += t;
        __syncthreads();
    }
    if (threadIdx.x < nb) bsum[threadIdx.x] = sh[threadIdx.x] - v;
}

__global__ void scan3_kernel(int* __restrict__ offs, const int* __restrict__ bsum,
                             int* __restrict__ cursor, int n, int E) {
    int i = blockIdx.x * NT + threadIdx.x;
    if (i < n) {
        int o = offs[i] + bsum[blockIdx.x];
        offs[i] = o;
        cursor[i] = o;
    }
    if (i == 0) offs[n] = E;
}

// Pass C: bucket-fill edge sources by dst.
__global__ void fill_kernel(const int* __restrict__ ei, int* __restrict__ cursor,
                            int* __restrict__ csr, int E) {
    for (int e = blockIdx.x * blockDim.x + threadIdx.x; e < E; e += gridDim.x * blockDim.x) {
        int dst = ei[E + e];
        int pos = atomicAdd(&cursor[dst], 1);
        csr[pos] = ei[e];
    }
}

// Pass D: pull-aggregate over bf16 x. One wave/node, uint (2 bf16) per lane.
// MEANBF=1: write bf16 mean to meanb; MEANBF=0: write f32 mean to meanf.
template <int MEANBF>
__global__ void aggregate_kernel(const unsigned short* __restrict__ xb,
                                 const int* __restrict__ offs, const int* __restrict__ csr,
                                 float* __restrict__ meanf, unsigned short* __restrict__ meanb,
                                 int n) {
    int wave = threadIdx.x >> 6;
    int lane = threadIdx.x & 63;
    int node = blockIdx.x * (blockDim.x >> 6) + wave;
    if (node >= n) return;
    int start = offs[node], end = offs[node + 1];
    const unsigned int* xu = reinterpret_cast<const unsigned int*>(xb);
    float ax = 0.f, ay = 0.f;
    int e = start;
    for (; e + 3 < end; e += 4) {
        unsigned int v0 = xu[(size_t)csr[e]     * 64 + lane];
        unsigned int v1 = xu[(size_t)csr[e + 1] * 64 + lane];
        unsigned int v2 = xu[(size_t)csr[e + 2] * 64 + lane];
        unsigned int v3 = xu[(size_t)csr[e + 3] * 64 + lane];
        ax += (bf16lo_to_f32(v0) + bf16lo_to_f32(v1)) + (bf16lo_to_f32(v2) + bf16lo_to_f32(v3));
        ay += (bf16hi_to_f32(v0) + bf16hi_to_f32(v1)) + (bf16hi_to_f32(v2) + bf16hi_to_f32(v3));
    }
    for (; e < end; ++e) {
        unsigned int v0 = xu[(size_t)csr[e] * 64 + lane];
        ax += bf16lo_to_f32(v0);
        ay += bf16hi_to_f32(v0);
    }
    float d = (float)(end - start);
    float inv = d > 0.f ? 1.0f / d : 0.f;
    ax *= inv; ay *= inv;
    if (MEANBF) {
        unsigned int pk = (unsigned int)f32_to_bf16(ax) | ((unsigned int)f32_to_bf16(ay) << 16);
        reinterpret_cast<unsigned int*>(meanb)[(size_t)node * 64 + lane] = pk;
    } else {
        reinterpret_cast<float2*>(meanf + (size_t)node * DIM)[lane] = make_float2(ax, ay);
    }
}

// Prep: pack W_B into bf16 MFMA B-fragment order + combined bias.
__global__ void prep_kernel(const float* __restrict__ w_self, const float* __restrict__ b_self,
                            const float* __restrict__ w_neigh, const float* __restrict__ b_neigh,
                            unsigned short* __restrict__ w_swz, float* __restrict__ bias) {
    int g = blockIdx.x * blockDim.x + threadIdx.x;
    if (g < 128) bias[g] = b_self[g] + b_neigh[g];
    if (g >= 64 * 64) return;
    int f = g >> 6, l = g & 63;
    int ks = f >> 3, nf = f & 7;
    int j = nf * 16 + (l & 15);
    int kbase = ks * 32 + ((l >> 4) << 3);
#pragma unroll
    for (int e = 0; e < 8; ++e) {
        int k = kbase + e;
        float v = (k < 128) ? w_self[(size_t)j * 128 + k] : w_neigh[(size_t)j * 128 + (k - 128)];
        w_swz[((size_t)g << 3) + e] = f32_to_bf16(v);
    }
}

// MFMA finalize: out = [x|mean]_bf16 @ W_B + bias.
// MEANBF=1: mean from bf16 ws buffer (no aliasing). MEANBF=0: mean f32 == out (in place).
#define FROWS 64
template <int MEANBF>
__global__ void finalize_kernel(const unsigned short* __restrict__ xb,
                                const float* __restrict__ meanf,
                                const unsigned short* __restrict__ meanb,
                                const unsigned short* __restrict__ w_swz,
                                const float* __restrict__ bias,
                                float* __restrict__ out, int n) {
    __shared__ unsigned short xm[FROWS][264];   // stride 132 dw -> 2-way max (free)
    int t = threadIdx.x;
    int base = blockIdx.x * FROWS;

    if (MEANBF) {
        // 32 chunks of 8 bf16 per row: c<16 -> x, c>=16 -> mean; dst offset = c*8 either way.
        for (int fi = t; fi < FROWS * 32; fi += NT) {
            int row = fi >> 5, c = fi & 31;
            int grow = base + row;
            ushort8 s = (ushort8)0;
            if (grow < n) {
                s = (c < 16)
                  ? reinterpret_cast<const ushort8*>(xb + (size_t)grow * DIM)[c]
                  : reinterpret_cast<const ushort8*>(meanb + (size_t)grow * DIM)[c - 16];
            }
            *reinterpret_cast<ushort8*>(&xm[row][c * 8]) = s;
        }
    } else {
        for (int fi = t; fi < FROWS * 16; fi += NT) {
            int row = fi >> 4, c = fi & 15;
            int grow = base + row;
            ushort8 s = (ushort8)0;
            if (grow < n) s = reinterpret_cast<const ushort8*>(xb + (size_t)grow * DIM)[c];
            *reinterpret_cast<ushort8*>(&xm[row][c * 8]) = s;
        }
        for (int fi = t; fi < FROWS * 32; fi += NT) {
            int row = fi >> 5, c4 = fi & 31;
            int grow = base + row;
            ushort4 sm = {0, 0, 0, 0};
            if (grow < n) {
                float4 mv = reinterpret_cast<const float4*>(meanf + (size_t)grow * DIM)[c4];
                sm = make_ushort4(f32_to_bf16(mv.x), f32_to_bf16(mv.y), f32_to_bf16(mv.z), f32_to_bf16(mv.w));
            }
            *reinterpret_cast<ushort4*>(&xm[row][128 + c4 * 4]) = sm;
        }
    }
    __syncthreads();

    int wave = t >> 6, lane = t & 63;
    int wrow = wave * 16;
    int arow = wrow + (lane & 15);
    int koff = (lane >> 4) << 3;

    f32x4 acc[8];
#pragma unroll
    for (int nf = 0; nf < 8; ++nf) acc[nf] = (f32x4){0.f, 0.f, 0.f, 0.f};

#pragma unroll
    for (int ks = 0; ks < 8; ++ks) {
        short8 a = *reinterpret_cast<const short8*>(&xm[arow][ks * 32 + koff]);
#pragma unroll
        for (int nf = 0; nf < 8; ++nf) {
            short8 b = *reinterpret_cast<const short8*>(
                w_swz + ((((size_t)ks * 8 + nf) * 64 + lane) << 3));
            acc[nf] = __builtin_amdgcn_mfma_f32_16x16x32_bf16(a, b, acc[nf], 0, 0, 0);
        }
    }

    int crow0 = wrow + ((lane >> 4) << 2);
#pragma unroll
    for (int nf = 0; nf < 8; ++nf) {
        int col = nf * 16 + (lane & 15);
        float bs = bias[col];
#pragma unroll
        for (int r = 0; r < 4; ++r) {
            int grow = base + crow0 + r;
            if (grow < n) out[(size_t)grow * DIM + col] = acc[nf][r] + bs;
        }
    }
}

extern "C" void kernel_launch(void* const* d_in, const int* in_sizes, int n_in,
                              void* d_out, int out_size, void* d_ws, size_t ws_size,
                              hipStream_t stream) {
    const float* x       = (const float*)d_in[0];
    const int*   ei      = (const int*)d_in[1];
    const float* w_self  = (const float*)d_in[2];
    const float* b_self  = (const float*)d_in[3];
    const float* w_neigh = (const float*)d_in[4];
    const float* b_neigh = (const float*)d_in[5];
    float* out = (float*)d_out;

    int n = in_sizes[0] / DIM;
    int E = in_sizes[1] / 2;
    int nb = (n + NT - 1) / NT;

    // ws: cnt[n] | offs[n+1] | cursor[n] | bsum[256] | csr[E] | w_swz bf16[32768] | bias f32[128]
    //     | x_bf bf16[n*128] | (optional) mean_bf bf16[n*128]
    int* cnt    = (int*)d_ws;
    int* offs   = cnt + n;
    int* cursor = offs + n + 1;
    int* bsum   = cursor + n;
    int* csr    = bsum + 256;
    unsigned short* w_swz = (unsigned short*)(((uintptr_t)(csr + E) + 15) & ~(uintptr_t)15);
    float* bias = (float*)(w_swz + 64 * 64 * 8);
    unsigned short* x_bf = (unsigned short*)(bias + 128);
    unsigned short* mean_bf = x_bf + (size_t)n * DIM;
    size_t need_full = (size_t)((char*)(mean_bf + (size_t)n * DIM) - (char*)d_ws);
    bool meanbf = ws_size >= need_full;

    hipMemsetAsync(cnt, 0, (size_t)n * sizeof(int), stream);

    prep_kernel<<<16, 256, 0, stream>>>(w_self, b_self, w_neigh, b_neigh, w_swz, bias);
    int n4 = n * DIM / 4;
    prepx_kernel<<<(n4 + NT - 1) / NT, NT, 0, stream>>>(x, x_bf, n4);

    int eblocks = (E + NT - 1) / NT;
    hist_kernel<<<eblocks, NT, 0, stream>>>(ei, cnt, E);
    scan1_kernel<<<nb, NT, 0, stream>>>(cnt, offs, bsum, n);
    scan2_kernel<<<1, NT, 0, stream>>>(bsum, nb);
    scan3_kernel<<<nb, NT, 0, stream>>>(offs, bsum, cursor, n, E);
    fill_kernel<<<eblocks, NT, 0, stream>>>(ei, cursor, csr, E);

    int ablocks = (n + 3) / 4;  // 1 node/wave, 4 waves/block
    int fblocks = (n + FROWS - 1) / FROWS;
    if (meanbf) {
        aggregate_kernel<1><<<ablocks, NT, 0, stream>>>(x_bf, offs, csr, nullptr, mean_bf, n);
        finalize_kernel<1><<<fblocks, NT, 0, stream>>>(x_bf, nullptr, mean_bf, w_swz, bias, out, n);
    } else {
        aggregate_kernel<0><<<ablocks, NT, 0, stream>>>(x_bf, offs, csr, out, nullptr, n);
        finalize_kernel<0><<<fblocks, NT, 0, stream>>>(x_bf, out, nullptr, w_swz, bias, out, n);
    }
}